// Round 11
// baseline (267.257 us; speedup 1.0000x reference)
//
#include <hip/hip_runtime.h>
#include <hip/hip_bf16.h>

// Flash-attention fwd, block-causal packed docs. fp32 HBM, bf16 MFMA.
// B=1, H=8, D=128. R20 = PROBE ROUND.
//  - R15/R19 falsified both "fill the SIMDs" and "amortize the step":
//    per-step cost scales with work, no pipe >30%, TLP doesn't help.
//    4 rounds of competing theories => measure, don't guess (R19
//    pre-commitment).
//  - Real pipeline (prepack + fa_fwd = R19 structure) runs unchanged for
//    correctness, except exp2f -> __builtin_amdgcn_exp2f (single
//    v_exp_f32; tests the VALU-inflation hypothesis: measured VALU issue
//    ~2.5x hand count, exp2f libcall expansion is prime suspect).
//  - PLUS 4 diagnostic clones (template<MODE,REP>), rep-looped so each
//    dispatch exceeds the 43us fill dispatches and appears in top-5 by
//    name; they write only to d_ws scratch:
//      dg<0,2> full loop x2           -> fa calib = dur/2
//      dg<1,2> NO gll16 staging x2    -> full - this = staging exposure
//      dg<3,2> NO softmax x2          -> full - this = softmax chain cost
//      dg<2,4> skeleton x4 (stage+waitcnt+barrier only) -> frame floor
//    DCE guards (rule 17): cross-rep checksum keeps MFMA chains live;
//    barrier asm "memory" clobber forces LDS re-reads each rep.
// Keeps: LPT dispatch order, BC=128 depth-1 pipeline, swapped-operand
// QK^T, P-in-registers PV, XOR-swizzled prepacked K/V^T, defer-rescale,
// setprio, LDS end-merge.

#define HD 128
#define BR 64
#define BC 128

typedef __attribute__((ext_vector_type(8))) short short8;
typedef __attribute__((ext_vector_type(4))) float floatx4;

__device__ inline unsigned packbf2(float lo, float hi) {
    __hip_bfloat162 h2 = __float22bfloat162_rn(make_float2(lo, hi));
    return *reinterpret_cast<unsigned*>(&h2);   // low16 = lo, high16 = hi
}
__device__ inline short bfs(float f) {
    __hip_bfloat16 b = __float2bfloat16(f);
    return *reinterpret_cast<short*>(&b);
}
__device__ inline float fexp2(float x) { return __builtin_amdgcn_exp2f(x); }

__device__ inline void gll16(const void* g, void* l) {
    __builtin_amdgcn_global_load_lds(
        (const __attribute__((address_space(1))) unsigned int*)g,
        (__attribute__((address_space(3))) unsigned int*)l, 16, 0, 0);
}

// ---------------- prepack: fp32 -> bf16, swizzled (V blocks first) --------
__global__ __launch_bounds__(256) void prepack(
    const float* __restrict__ K, const float* __restrict__ V,
    unsigned short* __restrict__ wsK, unsigned short* __restrict__ wsVT,
    int S)
{
    const int tid = threadIdx.x;
    const int nVblk = 8 * (S >> 6);
    const int bid = blockIdx.x;
    if (bid < nVblk) {
        __shared__ __align__(8) unsigned short sV[HD * 68];  // [d][r], stride 68 bf16
        const int ntile = S >> 6;
        const int h = bid / ntile;
        const int t = bid - h * ntile;
        const float* vb = V + ((size_t)h * S + t * 64) * HD;
        {
            const int rp = tid >> 3;
            const int dc = tid & 7;
            const int r0 = rp * 2;
            const int d0 = dc * 16;
            const float* p0 = vb + (size_t)r0 * HD + d0;
            const float* p1 = p0 + HD;
            float4 a0 = *(const float4*)(p0 + 0),  a1 = *(const float4*)(p0 + 4);
            float4 a2 = *(const float4*)(p0 + 8),  a3 = *(const float4*)(p0 + 12);
            float4 b0 = *(const float4*)(p1 + 0),  b1 = *(const float4*)(p1 + 4);
            float4 b2 = *(const float4*)(p1 + 8),  b3 = *(const float4*)(p1 + 12);
            float av[16] = {a0.x,a0.y,a0.z,a0.w, a1.x,a1.y,a1.z,a1.w,
                            a2.x,a2.y,a2.z,a2.w, a3.x,a3.y,a3.z,a3.w};
            float bv[16] = {b0.x,b0.y,b0.z,b0.w, b1.x,b1.y,b1.z,b1.w,
                            b2.x,b2.y,b2.z,b2.w, b3.x,b3.y,b3.z,b3.w};
            #pragma unroll
            for (int i = 0; i < 16; ++i) {
                unsigned pr = packbf2(av[i], bv[i]);   // keys r0 (lo), r0+1 (hi)
                *(unsigned*)((char*)sV + ((size_t)(d0 + i) * 68 + r0) * 2) = pr;
            }
        }
        __syncthreads();
        const int d  = tid >> 1;
        const int jj = tid & 1;
        char* dstrow = (char*)wsVT + (((size_t)(h * ntile + t) * HD + d) * 128);
        const int dx = (d & 7) << 4;
        const unsigned short* srow = sV + (size_t)d * 68;
        #pragma unroll
        for (int u = 0; u < 4; ++u) {
            const int j  = jj * 4 + u;
            const int k0 = (j >> 2) * 32 + (j & 3) * 4;
            uint2 lo = *(const uint2*)(srow + k0);
            uint2 hi = *(const uint2*)(srow + k0 + 16);
            uint4 w = make_uint4(lo.x, lo.y, hi.x, hi.y);
            *(uint4*)(dstrow + ((j * 16) ^ dx)) = w;
        }
    } else {
        const int cid = (bid - nVblk) * 256 + tid;
        const int row = cid >> 4;
        const int c   = cid & 15;
        const float* src = K + (size_t)row * HD + c * 8;
        float4 f0 = *(const float4*)src;
        float4 f1 = *(const float4*)(src + 4);
        union { uint4 q; unsigned u[4]; } w;
        w.u[0] = packbf2(f0.x, f0.y); w.u[1] = packbf2(f0.z, f0.w);
        w.u[2] = packbf2(f1.x, f1.y); w.u[3] = packbf2(f1.z, f1.w);
        *(uint4*)((char*)wsK + (size_t)row * 256 + ((c * 16) ^ ((row & 7) << 4))) = w.q;
    }
}

// ---------------- main attention kernel (R19 structure) ----------------
__global__ __launch_bounds__(512, 1) void fa_fwd(
    const float* __restrict__ Q,
    const unsigned short* __restrict__ wsK,
    const unsigned short* __restrict__ wsVT,
    const int* __restrict__ cu_seqlens, int n_cu,
    float* __restrict__ O,
    int S)
{
    __shared__ alignas(16) __hip_bfloat16 sK2[2][BC * HD];      // 2 x 32KB
    __shared__ alignas(16) unsigned int   sVT2[2][2 * HD * 32]; // 2 x 32KB

    const int tid  = threadIdx.x;
    const int wave = tid >> 6;
    const int gp   = wave >> 2;
    const int wsub = wave & 3;
    const int lane = tid & 63;
    const int quad = lane >> 4;
    const int l16  = lane & 15;
    const int kx   = (l16 & 7) << 4;

    const int nqb = S / BR;
    const int h   = blockIdx.x & 7;
    const int g   = (int)(blockIdx.x >> 3);
    int qb;
    if (nqb == 64) qb = (g & 3) * 16 + (15 - (g >> 2));   // LPT: nt desc
    else           qb = nqb - 1 - g;
    const int q0    = qb * BR;
    const int qw    = q0 + wsub * 16;
    const int qlane = qw + l16;

    int blk_ds = 0;
    for (int i = 0; i < n_cu; ++i) {
        int c = cu_seqlens[i];
        if (c <= q0) blk_ds = c;
    }
    const int k_begin = blk_ds & ~(BC - 1);
    const int ntiles  = (q0 + BR - 1 - k_begin) / BC + 1;

    const char* gkb = (const char*)wsK + (size_t)h * S * 256;
    const char* gvb = (const char*)wsVT + (size_t)h * (S >> 6) * 16384;
    const int wofs = (wave & 3) * 8192;
    const int lo = wofs + lane * 16;
    auto stage = [&](int kt, int buf) {
        if (gp == 0) {
            const char* gk = gkb + (size_t)kt * 256 + lo;
            char* lk = (char*)&sK2[buf][0] + wofs;
            #pragma unroll
            for (int c = 0; c < 8; ++c) gll16(gk + c * 1024, lk + c * 1024);
        } else {
            const char* gv = gvb + (size_t)(kt >> 6) * 16384 + lo;
            char* lv = (char*)&sVT2[buf][0] + wofs;
            #pragma unroll
            for (int c = 0; c < 8; ++c) gll16(gv + c * 1024, lv + c * 1024);
        }
    };

    const size_t hoff = (size_t)h * S * HD;
    const float* Qh = Q + hoff;
    float*       Oh = O + hoff;

    short8 aq[4];
    {
        const float* qp = Qh + (size_t)qlane * HD + quad * 8;
        #pragma unroll
        for (int ks = 0; ks < 4; ++ks) {
            float4 a0 = *(const float4*)(qp + ks * 32);
            float4 a1 = *(const float4*)(qp + ks * 32 + 4);
            short8 a;
            a[0] = bfs(a0.x); a[1] = bfs(a0.y); a[2] = bfs(a0.z); a[3] = bfs(a0.w);
            a[4] = bfs(a1.x); a[5] = bfs(a1.y); a[6] = bfs(a1.z); a[7] = bfs(a1.w);
            aq[ks] = a;
        }
    }

    int ds_lane = 0;
    for (int i = 0; i < n_cu; ++i) {
        int c = cu_seqlens[i];
        if (c <= qlane) ds_lane = c;
    }

    stage(k_begin, 0);

    floatx4 oacc[8];
    #pragma unroll
    for (int dt = 0; dt < 8; ++dt) oacc[dt] = (floatx4){0.f, 0.f, 0.f, 0.f};
    float m_r = -1e30f, l_r = 0.f;

    const float sl = 0.08838834764831845f * 1.4426950408889634f;

    for (int it = 0; it < ntiles; ++it) {
        const int kt  = k_begin + it * BC;
        const int buf = it & 1;

        asm volatile("s_waitcnt vmcnt(0)\n\ts_barrier" ::: "memory");
        if (it + 1 < ntiles) stage(kt + BC, buf ^ 1);

        if (kt + gp * 64 <= qw + 15) {
            const char* kbase = (const char*)&sK2[buf][0];
            const char* vbase = (const char*)&sVT2[buf][0] + gp * 16384;

            floatx4 sc[4];
            __builtin_amdgcn_s_setprio(1);
            #pragma unroll
            for (int ctl = 0; ctl < 4; ++ctl) {
                if (kt + gp * 64 + ctl * 16 <= qw + 15) {
                    floatx4 c = (floatx4){0.f, 0.f, 0.f, 0.f};
                    #pragma unroll
                    for (int ks = 0; ks < 4; ++ks) {
                        short8 a = *(const short8*)(kbase
                            + (gp * 64 + ctl * 16 + l16) * 256
                            + (((ks * 4 + quad) << 4) ^ kx));
                        c = __builtin_amdgcn_mfma_f32_16x16x32_bf16(a, aq[ks], c, 0, 0, 0);
                    }
                    sc[ctl] = c;
                } else {
                    sc[ctl] = (floatx4){-1e30f, -1e30f, -1e30f, -1e30f};
                }
            }
            __builtin_amdgcn_s_setprio(0);

            #pragma unroll
            for (int ctl = 0; ctl < 4; ++ctl) {
                if (kt + gp * 64 + ctl * 16 <= qw + 15) {
                    #pragma unroll
                    for (int r = 0; r < 4; ++r) {
                        const int key = kt + gp * 64 + ctl * 16 + quad * 4 + r;
                        const bool valid = (key <= qlane) && (key >= ds_lane);
                        float s = sc[ctl][r] * sl;
                        sc[ctl][r] = valid ? s : -1e30f;
                    }
                }
            }

            float mx01 = fmaxf(fmaxf(fmaxf(sc[0][0], sc[0][1]), fmaxf(sc[0][2], sc[0][3])),
                               fmaxf(fmaxf(sc[1][0], sc[1][1]), fmaxf(sc[1][2], sc[1][3])));
            float mx23 = fmaxf(fmaxf(fmaxf(sc[2][0], sc[2][1]), fmaxf(sc[2][2], sc[2][3])),
                               fmaxf(fmaxf(sc[3][0], sc[3][1]), fmaxf(sc[3][2], sc[3][3])));
            float mx = fmaxf(mx01, mx23);
            mx = fmaxf(mx, __shfl_xor(mx, 16, 64));
            mx = fmaxf(mx, __shfl_xor(mx, 32, 64));

            if (__any(mx > m_r + 8.f)) {
                const float mnew = fmaxf(m_r, mx);
                const float al   = fexp2(m_r - mnew);
                m_r = mnew;
                l_r *= al;
                #pragma unroll
                for (int dt = 0; dt < 8; ++dt) {
                    #pragma unroll
                    for (int r = 0; r < 4; ++r)
                        oacc[dt][r] *= al;
                }
            }
            const float live = (m_r > -1e29f) ? 1.f : 0.f;

            float ssum = 0.f;
            #pragma unroll
            for (int ctl = 0; ctl < 4; ++ctl) {
                #pragma unroll
                for (int r = 0; r < 4; ++r) {
                    float p = fexp2(sc[ctl][r] - m_r) * live;
                    sc[ctl][r] = p;
                    ssum += p;
                }
            }
            l_r += ssum;

            __builtin_amdgcn_s_setprio(1);
            #pragma unroll
            for (int ks = 0; ks < 2; ++ks) {
                if (kt + gp * 64 + ks * 32 <= qw + 15) {
                    union { unsigned u[4]; short8 s; } pu;
                    pu.u[0] = packbf2(sc[2*ks][0],   sc[2*ks][1]);
                    pu.u[1] = packbf2(sc[2*ks][2],   sc[2*ks][3]);
                    pu.u[2] = packbf2(sc[2*ks+1][0], sc[2*ks+1][1]);
                    pu.u[3] = packbf2(sc[2*ks+1][2], sc[2*ks+1][3]);
                    #pragma unroll
                    for (int dt = 0; dt < 8; ++dt) {
                        union { uint4 q; short8 s; } cv;
                        cv.q = *(const uint4*)(vbase + (dt * 16 + l16) * 128
                                               + (((ks * 4 + quad) << 4) ^ kx));
                        oacc[dt] = __builtin_amdgcn_mfma_f32_16x16x32_bf16(cv.s, pu.s, oacc[dt], 0, 0, 0);
                    }
                }
            }
            __builtin_amdgcn_s_setprio(0);
        }
    }

    l_r += __shfl_xor(l_r, 16, 64);
    l_r += __shfl_xor(l_r, 32, 64);

    __syncthreads();

    float* obuf = (float*)&sK2[0][0];
    float* lbuf = (float*)&sVT2[0][0];
    if (gp == 1) {
        float* ob = obuf + wsub * 2048;
        #pragma unroll
        for (int dt = 0; dt < 8; ++dt) {
            const int sw = (dt ^ (lane & 7)) << 2;
            float4 st;
            st.x = oacc[dt][0]; st.y = oacc[dt][1];
            st.z = oacc[dt][2]; st.w = oacc[dt][3];
            *(float4*)(ob + lane * 32 + sw) = st;
        }
        if (quad == 0) {
            lbuf[wsub * 128 + l16]      = m_r;
            lbuf[wsub * 128 + 64 + l16] = l_r;
        }
    }
    __syncthreads();
    if (gp == 0) {
        const float m2 = lbuf[wsub * 128 + l16];
        const float l2 = lbuf[wsub * 128 + 64 + l16];
        const float M  = fmaxf(m_r, m2);
        const float w1 = fexp2(m_r - M);
        const float w2 = fexp2(m2 - M);
        const float inv = 1.0f / (w1 * l_r + w2 * l2);
        const float* ob = obuf + wsub * 2048;
        float* op = Oh + (size_t)qlane * HD + quad * 4;
        #pragma unroll
        for (int dt = 0; dt < 8; ++dt) {
            const int sw = (dt ^ (lane & 7)) << 2;
            float4 o2 = *(const float4*)(ob + lane * 32 + sw);
            float4 st;
            st.x = (w1 * oacc[dt][0] + w2 * o2.x) * inv;
            st.y = (w1 * oacc[dt][1] + w2 * o2.y) * inv;
            st.z = (w1 * oacc[dt][2] + w2 * o2.z) * inv;
            st.w = (w1 * oacc[dt][3] + w2 * o2.w) * inv;
            *(float4*)(op + dt * 16) = st;
        }
    }
}

// ---------------- diagnostic ablation clones (write scratch only) ---------
// MODE 0=full  1=no-staging  2=skeleton-only  3=no-softmax
template<int MODE, int REP>
__global__ __launch_bounds__(512, 1) void dg(
    const float* __restrict__ Q,
    const unsigned short* __restrict__ wsK,
    const unsigned short* __restrict__ wsVT,
    const int* __restrict__ cu_seqlens, int n_cu,
    float* __restrict__ scratch,
    int S)
{
    __shared__ alignas(16) __hip_bfloat16 sK2[2][BC * HD];
    __shared__ alignas(16) unsigned int   sVT2[2][2 * HD * 32];

    const int tid  = threadIdx.x;
    const int wave = tid >> 6;
    const int gp   = wave >> 2;
    const int wsub = wave & 3;
    const int lane = tid & 63;
    const int quad = lane >> 4;
    const int l16  = lane & 15;
    const int kx   = (l16 & 7) << 4;

    const int nqb = S / BR;
    const int h   = blockIdx.x & 7;
    const int g   = (int)(blockIdx.x >> 3);
    int qb;
    if (nqb == 64) qb = (g & 3) * 16 + (15 - (g >> 2));
    else           qb = nqb - 1 - g;
    const int q0    = qb * BR;
    const int qw    = q0 + wsub * 16;
    const int qlane = qw + l16;

    int blk_ds = 0;
    for (int i = 0; i < n_cu; ++i) {
        int c = cu_seqlens[i];
        if (c <= q0) blk_ds = c;
    }
    const int k_begin = blk_ds & ~(BC - 1);
    const int ntiles  = (q0 + BR - 1 - k_begin) / BC + 1;

    const char* gkb = (const char*)wsK + (size_t)h * S * 256;
    const char* gvb = (const char*)wsVT + (size_t)h * (S >> 6) * 16384;
    const int wofs = (wave & 3) * 8192;
    const int lo = wofs + lane * 16;
    auto stage = [&](int kt, int buf) {
        if (gp == 0) {
            const char* gk = gkb + (size_t)kt * 256 + lo;
            char* lk = (char*)&sK2[buf][0] + wofs;
            #pragma unroll
            for (int c = 0; c < 8; ++c) gll16(gk + c * 1024, lk + c * 1024);
        } else {
            const char* gv = gvb + (size_t)(kt >> 6) * 16384 + lo;
            char* lv = (char*)&sVT2[buf][0] + wofs;
            #pragma unroll
            for (int c = 0; c < 8; ++c) gll16(gv + c * 1024, lv + c * 1024);
        }
    };

    short8 aq[4];
    {
        const float* qp = Q + (size_t)h * S * HD + (size_t)qlane * HD + quad * 8;
        #pragma unroll
        for (int ks = 0; ks < 4; ++ks) {
            float4 a0 = *(const float4*)(qp + ks * 32);
            float4 a1 = *(const float4*)(qp + ks * 32 + 4);
            short8 a;
            a[0] = bfs(a0.x); a[1] = bfs(a0.y); a[2] = bfs(a0.z); a[3] = bfs(a0.w);
            a[4] = bfs(a1.x); a[5] = bfs(a1.y); a[6] = bfs(a1.z); a[7] = bfs(a1.w);
            aq[ks] = a;
        }
    }

    int ds_lane = 0;
    for (int i = 0; i < n_cu; ++i) {
        int c = cu_seqlens[i];
        if (c <= qlane) ds_lane = c;
    }

    const float sl = 0.08838834764831845f * 1.4426950408889634f;
    float chk = 0.f;                      // cross-rep DCE guard (rule 17)

    for (int rep = 0; rep < REP; ++rep) {
        floatx4 oacc[8];
        #pragma unroll
        for (int dt = 0; dt < 8; ++dt) oacc[dt] = (floatx4){0.f, 0.f, 0.f, 0.f};
        float m_r = -1e30f, l_r = 0.f;

        if (MODE != 1) stage(k_begin, 0);

        for (int it = 0; it < ntiles; ++it) {
            const int kt  = k_begin + it * BC;
            const int buf = it & 1;

            asm volatile("s_waitcnt vmcnt(0)\n\ts_barrier" ::: "memory");
            if (MODE != 1 && it + 1 < ntiles) stage(kt + BC, buf ^ 1);

            if (MODE != 2 && kt + gp * 64 <= qw + 15) {
                const char* kbase = (const char*)&sK2[buf][0];
                const char* vbase = (const char*)&sVT2[buf][0] + gp * 16384;

                floatx4 sc[4];
                __builtin_amdgcn_s_setprio(1);
                #pragma unroll
                for (int ctl = 0; ctl < 4; ++ctl) {
                    if (kt + gp * 64 + ctl * 16 <= qw + 15) {
                        floatx4 c = (floatx4){0.f, 0.f, 0.f, 0.f};
                        #pragma unroll
                        for (int ks = 0; ks < 4; ++ks) {
                            short8 a = *(const short8*)(kbase
                                + (gp * 64 + ctl * 16 + l16) * 256
                                + (((ks * 4 + quad) << 4) ^ kx));
                            c = __builtin_amdgcn_mfma_f32_16x16x32_bf16(a, aq[ks], c, 0, 0, 0);
                        }
                        sc[ctl] = c;
                    } else {
                        sc[ctl] = (floatx4){-1e30f, -1e30f, -1e30f, -1e30f};
                    }
                }
                __builtin_amdgcn_s_setprio(0);

                #pragma unroll
                for (int ctl = 0; ctl < 4; ++ctl) {
                    if (kt + gp * 64 + ctl * 16 <= qw + 15) {
                        #pragma unroll
                        for (int r = 0; r < 4; ++r) {
                            const int key = kt + gp * 64 + ctl * 16 + quad * 4 + r;
                            const bool valid = (key <= qlane) && (key >= ds_lane);
                            float s = sc[ctl][r] * sl;
                            sc[ctl][r] = valid ? s : -1e30f;
                        }
                    }
                }

                if (MODE != 3) {
                    float mx01 = fmaxf(fmaxf(fmaxf(sc[0][0], sc[0][1]), fmaxf(sc[0][2], sc[0][3])),
                                       fmaxf(fmaxf(sc[1][0], sc[1][1]), fmaxf(sc[1][2], sc[1][3])));
                    float mx23 = fmaxf(fmaxf(fmaxf(sc[2][0], sc[2][1]), fmaxf(sc[2][2], sc[2][3])),
                                       fmaxf(fmaxf(sc[3][0], sc[3][1]), fmaxf(sc[3][2], sc[3][3])));
                    float mx = fmaxf(mx01, mx23);
                    mx = fmaxf(mx, __shfl_xor(mx, 16, 64));
                    mx = fmaxf(mx, __shfl_xor(mx, 32, 64));

                    if (__any(mx > m_r + 8.f)) {
                        const float mnew = fmaxf(m_r, mx);
                        const float al   = fexp2(m_r - mnew);
                        m_r = mnew;
                        l_r *= al;
                        #pragma unroll
                        for (int dt = 0; dt < 8; ++dt) {
                            #pragma unroll
                            for (int r = 0; r < 4; ++r)
                                oacc[dt][r] *= al;
                        }
                    }
                    const float live = (m_r > -1e29f) ? 1.f : 0.f;
                    float ssum = 0.f;
                    #pragma unroll
                    for (int ctl = 0; ctl < 4; ++ctl) {
                        #pragma unroll
                        for (int r = 0; r < 4; ++r) {
                            float p = fexp2(sc[ctl][r] - m_r) * live;
                            sc[ctl][r] = p;
                            ssum += p;
                        }
                    }
                    l_r += ssum;
                } else {
                    // no-softmax: bounded passthrough keeps pack+PV live
                    #pragma unroll
                    for (int ctl = 0; ctl < 4; ++ctl) {
                        #pragma unroll
                        for (int r = 0; r < 4; ++r) {
                            float p = sc[ctl][r] * 0.0625f;
                            sc[ctl][r] = p;
                            l_r += p;
                        }
                    }
                }

                __builtin_amdgcn_s_setprio(1);
                #pragma unroll
                for (int ks = 0; ks < 2; ++ks) {
                    if (kt + gp * 64 + ks * 32 <= qw + 15) {
                        union { unsigned u[4]; short8 s; } pu;
                        pu.u[0] = packbf2(sc[2*ks][0],   sc[2*ks][1]);
                        pu.u[1] = packbf2(sc[2*ks][2],   sc[2*ks][3]);
                        pu.u[2] = packbf2(sc[2*ks+1][0], sc[2*ks+1][1]);
                        pu.u[3] = packbf2(sc[2*ks+1][2], sc[2*ks+1][3]);
                        #pragma unroll
                        for (int dt = 0; dt < 8; ++dt) {
                            union { uint4 q; short8 s; } cv;
                            cv.q = *(const uint4*)(vbase + (dt * 16 + l16) * 128
                                                   + (((ks * 4 + quad) << 4) ^ kx));
                            oacc[dt] = __builtin_amdgcn_mfma_f32_16x16x32_bf16(cv.s, pu.s, oacc[dt], 0, 0, 0);
                        }
                    }
                }
                __builtin_amdgcn_s_setprio(0);
            }
        }

        // keep this rep's computation live
        #pragma unroll
        for (int dt = 0; dt < 8; ++dt)
            chk += oacc[dt][0] + oacc[dt][3];
        chk += m_r + l_r;
        if (MODE == 2) chk += ((float*)&sK2[0][0])[tid];   // touch staged LDS
    }

    scratch[(size_t)blockIdx.x * 512 + tid] = chk;
}

extern "C" void kernel_launch(void* const* d_in, const int* in_sizes, int n_in,
                              void* d_out, int out_size, void* d_ws, size_t ws_size,
                              hipStream_t stream) {
    const float* q = (const float*)d_in[0];
    const float* k = (const float*)d_in[1];
    const float* v = (const float*)d_in[2];
    const int* cu = (const int*)d_in[3];
    const int n_cu = in_sizes[3];
    const int H = 8;
    const int S = in_sizes[0] / (H * HD);   // B=1
    float* out = (float*)d_out;

    const int nqb = S / BR;
    unsigned short* wsK  = (unsigned short*)d_ws;                 // H*S*256 B
    unsigned short* wsVT = wsK + (size_t)H * S * HD;              // H*S*256 B

    const int nVblk = H * (S >> 6);          // 512
    const int nKblk = (H * S) / 16;          // 2048
    prepack<<<dim3(nVblk + nKblk), dim3(256), 0, stream>>>(k, v, wsK, wsVT, S);

    dim3 grid(H * nqb);        // 512 blocks
    dim3 block(512);           // 8 waves
    fa_fwd<<<grid, block, 0, stream>>>(q, wsK, wsVT, cu, n_cu, out, S);

    // ---- diagnostic dispatches (probe round; write d_ws scratch only) ----
    const size_t scratch_off = (size_t)100 << 20;
    if (ws_size >= scratch_off + ((size_t)8 << 20)) {
        float* dgs = (float*)((char*)d_ws + scratch_off);
        dg<0, 2><<<grid, block, 0, stream>>>(q, wsK, wsVT, cu, n_cu, dgs, S);
        dg<1, 2><<<grid, block, 0, stream>>>(q, wsK, wsVT, cu, n_cu, dgs, S);
        dg<3, 2><<<grid, block, 0, stream>>>(q, wsK, wsVT, cu, n_cu, dgs, S);
        dg<2, 4><<<grid, block, 0, stream>>>(q, wsK, wsVT, cu, n_cu, dgs, S);
    }
}

// Round 12
// 185.431 us; speedup vs baseline: 1.4413x; 1.4413x over previous
//
#include <hip/hip_runtime.h>
#include <hip/hip_bf16.h>

// Flash-attention fwd, block-causal packed docs. fp32 HBM, bf16 MFMA.
// B=1, H=8, D=128. R21: NO-LDS direct-from-L2 K/V reads + XCD-local prepack.
//  - R20 probe: staging = ~40% of loop (dg<1> fast), softmax ~ free (dg<3>
//    = dg<0>), frame small (dg<2> ~3.7us/rep). AND dg full-loop rep = 24.4us
//    vs real fa_fwd 39.5us => ~15us is cross-XCD L2 first-touch (prepack
//    wrote head h's data on the wrong XCD; fa_fwd reads it cross-die).
//  - Fix 1 (guide mistake #7): per-head K/V = 2MB << 4MB XCD L2 -> read
//    MFMA fragments DIRECTLY from prepacked global buffers. Per-(l16) the
//    4 quads read contiguous 64B; wave = 16 x 64B segments. No gll16, no
//    vmcnt, no double buffer, ZERO in-loop barriers (one syncthreads pair
//    at end-merge). XOR swizzle dropped BOTH sides (no LDS -> no banks).
//    LDS = 34KB merge buffer only; waves fully decoupled, 4 waves/SIMD
//    of independent TLP (launch_bounds(512,4) caps VGPR 128).
//  - Fix 2: prepack remapped so head h's writer blocks have blockIdx%8==h
//    (same XCD as fa_fwd's h=blockIdx&7 consumers): data lands dirty in
//    the CONSUMING XCD's L2.
// Keeps: LPT dispatch order (nt desc), BC=128 with 8-wave key-split
// (gp=key-half, wsub=query-16), swapped-operand QK^T, P-in-registers PV,
// T13 defer-rescale, exp2 builtin, setprio on MFMA, LDS end-merge.

#define HD 128
#define BR 64
#define BC 128

typedef __attribute__((ext_vector_type(8))) short short8;
typedef __attribute__((ext_vector_type(4))) float floatx4;

__device__ inline unsigned packbf2(float lo, float hi) {
    __hip_bfloat162 h2 = __float22bfloat162_rn(make_float2(lo, hi));
    return *reinterpret_cast<unsigned*>(&h2);   // low16 = lo, high16 = hi
}
__device__ inline short bfs(float f) {
    __hip_bfloat16 b = __float2bfloat16(f);
    return *reinterpret_cast<short*>(&b);
}
__device__ inline float fexp2(float x) { return __builtin_amdgcn_exp2f(x); }

// ---------------- prepack: fp32 -> bf16, XCD-local, NO swizzle ------------
// Block->XCD assumed blockIdx%8; all writer blocks for head h use bid&7==h
// so wsK/wsVT land dirty in the L2 that fa_fwd's head-h blocks read.
__global__ __launch_bounds__(256) void prepack(
    const float* __restrict__ K, const float* __restrict__ V,
    unsigned short* __restrict__ wsK, unsigned short* __restrict__ wsVT,
    int S)
{
    const int tid = threadIdx.x;
    const int nVblk = 8 * (S >> 6);
    const int bid = blockIdx.x;
    if (bid < nVblk) {
        // V^T via LDS: block = (h = bid&7, t = bid>>3).
        __shared__ __align__(8) unsigned short sV[HD * 68];  // [d][r], stride 68 bf16
        const int ntile = S >> 6;
        const int h = bid & 7;
        const int t = bid >> 3;
        const float* vb = V + ((size_t)h * S + t * 64) * HD;
        {
            const int rp = tid >> 3;
            const int dc = tid & 7;
            const int r0 = rp * 2;
            const int d0 = dc * 16;
            const float* p0 = vb + (size_t)r0 * HD + d0;
            const float* p1 = p0 + HD;
            float4 a0 = *(const float4*)(p0 + 0),  a1 = *(const float4*)(p0 + 4);
            float4 a2 = *(const float4*)(p0 + 8),  a3 = *(const float4*)(p0 + 12);
            float4 b0 = *(const float4*)(p1 + 0),  b1 = *(const float4*)(p1 + 4);
            float4 b2 = *(const float4*)(p1 + 8),  b3 = *(const float4*)(p1 + 12);
            float av[16] = {a0.x,a0.y,a0.z,a0.w, a1.x,a1.y,a1.z,a1.w,
                            a2.x,a2.y,a2.z,a2.w, a3.x,a3.y,a3.z,a3.w};
            float bv[16] = {b0.x,b0.y,b0.z,b0.w, b1.x,b1.y,b1.z,b1.w,
                            b2.x,b2.y,b2.z,b2.w, b3.x,b3.y,b3.z,b3.w};
            #pragma unroll
            for (int i = 0; i < 16; ++i) {
                unsigned pr = packbf2(av[i], bv[i]);   // keys r0 (lo), r0+1 (hi)
                *(unsigned*)((char*)sV + ((size_t)(d0 + i) * 68 + r0) * 2) = pr;
            }
        }
        __syncthreads();
        // chunk j=ks*4+q at byte j*16: dwords = keys 32ks+4q+{0,1},{2,3},
        // +16+{0,1}, +16+{2,3}.  (B-frag key order of the PV A-operand.)
        const int d  = tid >> 1;
        const int jj = tid & 1;
        char* dstrow = (char*)wsVT + (((size_t)(h * ntile + t) * HD + d) * 128);
        const unsigned short* srow = sV + (size_t)d * 68;
        #pragma unroll
        for (int u = 0; u < 4; ++u) {
            const int j  = jj * 4 + u;
            const int k0 = (j >> 2) * 32 + (j & 3) * 4;
            uint2 lo = *(const uint2*)(srow + k0);        // keys k0..k0+3
            uint2 hi = *(const uint2*)(srow + k0 + 16);   // keys k0+16..k0+19
            uint4 w = make_uint4(lo.x, lo.y, hi.x, hi.y);
            *(uint4*)(dstrow + j * 16) = w;
        }
    } else {
        // K: block = (h = b2&7, idx = b2>>3); one 16B chunk per thread.
        const int b2  = bid - nVblk;
        const int h   = b2 & 7;
        const int idx = b2 >> 3;                // 0..(S*16/256)-1
        const int cid = idx * 256 + tid;        // chunk id within head
        const int rowh = cid >> 4;              // row within head
        const int c    = cid & 15;
        const size_t row = (size_t)h * S + rowh;
        const float* src = K + row * HD + c * 8;
        float4 f0 = *(const float4*)src;
        float4 f1 = *(const float4*)(src + 4);
        union { uint4 q; unsigned u[4]; } w;
        w.u[0] = packbf2(f0.x, f0.y); w.u[1] = packbf2(f0.z, f0.w);
        w.u[2] = packbf2(f1.x, f1.y); w.u[3] = packbf2(f1.z, f1.w);
        *(uint4*)((char*)wsK + row * 256 + c * 16) = w.q;
    }
}

// ---------------- main attention kernel (no staging, no in-loop sync) -----
__global__ __launch_bounds__(512, 4) void fa_fwd(
    const float* __restrict__ Q,
    const unsigned short* __restrict__ wsK,
    const unsigned short* __restrict__ wsVT,
    const int* __restrict__ cu_seqlens, int n_cu,
    float* __restrict__ O,
    int S)
{
    __shared__ alignas(16) float obuf[4 * 2048];   // 32KB: 4 pairs x O-partial
    __shared__ alignas(16) float lbuf[4 * 128];    //  2KB: m/l per pair

    const int tid  = threadIdx.x;
    const int wave = tid >> 6;
    const int gp   = wave >> 2;             // key-half group 0/1 (64 keys each)
    const int wsub = wave & 3;              // query sub-block 0..3
    const int lane = tid & 63;
    const int quad = lane >> 4;
    const int l16  = lane & 15;

    const int nqb = S / BR;
    const int h   = blockIdx.x & 7;         // head -> XCD (matches prepack)
    const int g   = (int)(blockIdx.x >> 3);
    // LPT dispatch order: nt128 non-increasing (R18 lesson: CP refills CUs
    // dynamically in dispatch order; heavy chains first).
    int qb;
    if (nqb == 64) qb = (g & 3) * 16 + (15 - (g >> 2));
    else           qb = nqb - 1 - g;
    const int q0    = qb * BR;
    const int qw    = q0 + wsub * 16;
    const int qlane = qw + l16;     // the ONE query this lane owns

    int blk_ds = 0;
    for (int i = 0; i < n_cu; ++i) {
        int c = cu_seqlens[i];
        if (c <= q0) blk_ds = c;
    }
    const int k_begin = blk_ds & ~(BC - 1);
    const int ntiles  = (q0 + BR - 1 - k_begin) / BC + 1;

    const char* gkb = (const char*)wsK + (size_t)h * S * 256;
    const char* gvb = (const char*)wsVT + (size_t)h * (S >> 6) * 16384;

    const size_t hoff = (size_t)h * S * HD;
    const float* Qh = Q + hoff;
    float*       Oh = O + hoff;

    // ---- Q fragments (B-operand: lane holds Q[qlane][ks*32+quad*8+j]) ----
    short8 aq[4];
    {
        const float* qp = Qh + (size_t)qlane * HD + quad * 8;
        #pragma unroll
        for (int ks = 0; ks < 4; ++ks) {
            float4 a0 = *(const float4*)(qp + ks * 32);
            float4 a1 = *(const float4*)(qp + ks * 32 + 4);
            short8 a;
            a[0] = bfs(a0.x); a[1] = bfs(a0.y); a[2] = bfs(a0.z); a[3] = bfs(a0.w);
            a[4] = bfs(a1.x); a[5] = bfs(a1.y); a[6] = bfs(a1.z); a[7] = bfs(a1.w);
            aq[ks] = a;
        }
    }

    int ds_lane = 0;
    for (int i = 0; i < n_cu; ++i) {
        int c = cu_seqlens[i];
        if (c <= qlane) ds_lane = c;
    }

    // oacc[dt][r] = O^T partial for THIS key-half: d=dt*16+quad*4+r, q=qlane
    floatx4 oacc[8];
    #pragma unroll
    for (int dt = 0; dt < 8; ++dt) oacc[dt] = (floatx4){0.f, 0.f, 0.f, 0.f};
    float m_r = -1e30f, l_r = 0.f;

    const float sl = 0.08838834764831845f * 1.4426950408889634f;

    for (int it = 0; it < ntiles; ++it) {
        const int kt = k_begin + it * BC;
        if (kt + gp * 64 > qw + 15) continue;    // wave-uniform key-half gate

        // per-(l16): quads read contiguous 64B; wave = 16 x 64B segments.
        const char* ktb = gkb + (size_t)(kt + gp * 64) * 256;
        const char* vtb = gvb + (size_t)((kt >> 6) + gp) * 16384;

        // ---- S^T = K Q^T over this wave's 64 keys (4 ct blocks) ----
        floatx4 sc[4];
        __builtin_amdgcn_s_setprio(1);
        #pragma unroll
        for (int ctl = 0; ctl < 4; ++ctl) {
            if (kt + gp * 64 + ctl * 16 <= qw + 15) {   // wave-uniform
                short8 a[4];
                #pragma unroll
                for (int ks = 0; ks < 4; ++ks)
                    a[ks] = *(const short8*)(ktb + (ctl * 16 + l16) * 256
                                             + (ks * 4 + quad) * 16);
                floatx4 c = (floatx4){0.f, 0.f, 0.f, 0.f};
                #pragma unroll
                for (int ks = 0; ks < 4; ++ks)
                    c = __builtin_amdgcn_mfma_f32_16x16x32_bf16(a[ks], aq[ks], c, 0, 0, 0);
                sc[ctl] = c;
            } else {
                sc[ctl] = (floatx4){-1e30f, -1e30f, -1e30f, -1e30f};
            }
        }
        __builtin_amdgcn_s_setprio(0);

        // ---- mask + scale ----
        #pragma unroll
        for (int ctl = 0; ctl < 4; ++ctl) {
            if (kt + gp * 64 + ctl * 16 <= qw + 15) {
                #pragma unroll
                for (int r = 0; r < 4; ++r) {
                    const int key = kt + gp * 64 + ctl * 16 + quad * 4 + r;
                    const bool valid = (key <= qlane) && (key >= ds_lane);
                    float s = sc[ctl][r] * sl;
                    sc[ctl][r] = valid ? s : -1e30f;
                }
            }
        }

        // ---- online softmax over 16 values + 2 shfl ----
        float mx01 = fmaxf(fmaxf(fmaxf(sc[0][0], sc[0][1]), fmaxf(sc[0][2], sc[0][3])),
                           fmaxf(fmaxf(sc[1][0], sc[1][1]), fmaxf(sc[1][2], sc[1][3])));
        float mx23 = fmaxf(fmaxf(fmaxf(sc[2][0], sc[2][1]), fmaxf(sc[2][2], sc[2][3])),
                           fmaxf(fmaxf(sc[3][0], sc[3][1]), fmaxf(sc[3][2], sc[3][3])));
        float mx = fmaxf(mx01, mx23);
        mx = fmaxf(mx, __shfl_xor(mx, 16, 64));
        mx = fmaxf(mx, __shfl_xor(mx, 32, 64));

        // T13 defer-rescale: skip oacc/l rescale unless max moved > 8.
        if (__any(mx > m_r + 8.f)) {
            const float mnew = fmaxf(m_r, mx);
            const float al   = fexp2(m_r - mnew);
            m_r = mnew;
            l_r *= al;
            #pragma unroll
            for (int dt = 0; dt < 8; ++dt) {
                #pragma unroll
                for (int r = 0; r < 4; ++r)
                    oacc[dt][r] *= al;
            }
        }
        const float live = (m_r > -1e29f) ? 1.f : 0.f;  // key-half never valid

        float ssum = 0.f;
        #pragma unroll
        for (int ctl = 0; ctl < 4; ++ctl) {
            #pragma unroll
            for (int r = 0; r < 4; ++r) {
                float p = fexp2(sc[ctl][r] - m_r) * live;
                sc[ctl][r] = p;
                ssum += p;
            }
        }
        l_r += ssum;

        // ---- O^T += V^T P^T over this wave's 64-key V tile ----
        __builtin_amdgcn_s_setprio(1);
        #pragma unroll
        for (int ks = 0; ks < 2; ++ks) {
            if (kt + gp * 64 + ks * 32 <= qw + 15) {    // wave-uniform
                union { unsigned u[4]; short8 s; } pu;  // B-frag = own p's
                pu.u[0] = packbf2(sc[2*ks][0],   sc[2*ks][1]);
                pu.u[1] = packbf2(sc[2*ks][2],   sc[2*ks][3]);
                pu.u[2] = packbf2(sc[2*ks+1][0], sc[2*ks+1][1]);
                pu.u[3] = packbf2(sc[2*ks+1][2], sc[2*ks+1][3]);
                #pragma unroll
                for (int dt = 0; dt < 8; ++dt) {
                    union { uint4 q; short8 s; } cv;
                    cv.q = *(const uint4*)(vtb + (dt * 16 + l16) * 128
                                           + (ks * 4 + quad) * 16);
                    oacc[dt] = __builtin_amdgcn_mfma_f32_16x16x32_bf16(cv.s, pu.s, oacc[dt], 0, 0, 0);
                }
            }
        }
        __builtin_amdgcn_s_setprio(0);
    }

    // ---- reduce l over quads (within key-half) ----
    l_r += __shfl_xor(l_r, 16, 64);
    l_r += __shfl_xor(l_r, 32, 64);

    // ---- cross-group merge via LDS (pair = waves wsub, wsub+4) ----
    // exact regardless of whether m_r is the true max (reference-point
    // identity: w = exp2(m_r - M); l/oacc are relative to m_r).
    if (gp == 1) {
        float* ob = obuf + wsub * 2048;
        #pragma unroll
        for (int dt = 0; dt < 8; ++dt) {
            const int sw = (dt ^ (lane & 7)) << 2;
            float4 st;
            st.x = oacc[dt][0]; st.y = oacc[dt][1];
            st.z = oacc[dt][2]; st.w = oacc[dt][3];
            *(float4*)(ob + lane * 32 + sw) = st;
        }
        if (quad == 0) {
            lbuf[wsub * 128 + l16]      = m_r;
            lbuf[wsub * 128 + 64 + l16] = l_r;
        }
    }
    __syncthreads();
    if (gp == 0) {
        const float m2 = lbuf[wsub * 128 + l16];
        const float l2 = lbuf[wsub * 128 + 64 + l16];
        const float M  = fmaxf(m_r, m2);
        const float w1 = fexp2(m_r - M);
        const float w2 = fexp2(m2 - M);
        const float inv = 1.0f / (w1 * l_r + w2 * l2);
        const float* ob = obuf + wsub * 2048;
        float* op = Oh + (size_t)qlane * HD + quad * 4;
        #pragma unroll
        for (int dt = 0; dt < 8; ++dt) {
            const int sw = (dt ^ (lane & 7)) << 2;
            float4 o2 = *(const float4*)(ob + lane * 32 + sw);
            float4 st;
            st.x = (w1 * oacc[dt][0] + w2 * o2.x) * inv;
            st.y = (w1 * oacc[dt][1] + w2 * o2.y) * inv;
            st.z = (w1 * oacc[dt][2] + w2 * o2.z) * inv;
            st.w = (w1 * oacc[dt][3] + w2 * o2.w) * inv;
            *(float4*)(op + dt * 16) = st;
        }
    }
}

extern "C" void kernel_launch(void* const* d_in, const int* in_sizes, int n_in,
                              void* d_out, int out_size, void* d_ws, size_t ws_size,
                              hipStream_t stream) {
    const float* q = (const float*)d_in[0];
    const float* k = (const float*)d_in[1];
    const float* v = (const float*)d_in[2];
    const int* cu = (const int*)d_in[3];
    const int n_cu = in_sizes[3];
    const int H = 8;
    const int S = in_sizes[0] / (H * HD);   // B=1
    float* out = (float*)d_out;

    const int nqb = S / BR;
    unsigned short* wsK  = (unsigned short*)d_ws;                 // H*S*256 B
    unsigned short* wsVT = wsK + (size_t)H * S * HD;              // H*S*256 B

    const int nVblk = H * (S >> 6);          // 512 (V blocks first)
    const int nKblk = (H * S) / 16;          // 2048
    prepack<<<dim3(nVblk + nKblk), dim3(256), 0, stream>>>(k, v, wsK, wsVT, S);

    dim3 grid(H * nqb);        // 512 blocks, 2/CU (34KB LDS, 128 VGPR cap)
    dim3 block(512);           // 8 waves
    fa_fwd<<<grid, block, 0, stream>>>(q, wsK, wsVT, cu, n_cu, out, S);
}

// Round 13
// 124.015 us; speedup vs baseline: 2.1550x; 1.4952x over previous
//
#include <hip/hip_runtime.h>
#include <hip/hip_bf16.h>

// Flash-attention fwd, block-causal packed docs. fp32 HBM, bf16 MFMA.
// B=1, H=8, D=128. R22 = R19 (best: harness 126.5, fa ~39.5) + XCD-LOCAL
// PREPACK + mask/scale hoisting. Minimal diff round.
//  - R21 post-mortem: R20 probe re-read — dg<0>=dg<1>=dg<3>=24.4us/rep:
//    staging ~FREE, softmax ~free; core = LDS-reads+MFMA+mask/pack.
//    R21's direct-global reads (4x redundant, latency-exposed) were a
//    misread-driven regression (96us). LDS staging restored (R19 form).
//  - Remaining 15us gap real-fa(39.5) vs warm-clone(24.4): cross-XCD
//    first-touch — old prepack wrote head h's K/V from blocks on ALL 8
//    XCDs; fa_fwd's head-h readers sit on XCD h (h=blockIdx&7). Fix:
//    remap prepack writers so bid&7==h (V: t=bid>>3; K: idx=b2>>3) —
//    SAME swizzled layout, only block->data assignment changes.
//  - Mask hoisting: sl*log2e folded into Q fragments at conversion;
//    per-ct wave-uniform `full=(kc+15<=qw && kc>=blk_ds)` skips the
//    32-op mask entirely on non-diagonal blocks (diag only pays).
//  - exp2f -> __builtin_amdgcn_exp2f.
// Keeps from R19: BC=128 2-buffer depth-1 pipeline (stage(t+1) issued
// post-barrier; step-top vmcnt(0) covers loads issued a full step ago),
// LPT dispatch order (nt desc), 8-wave key-split (gp=64-key half, wsub=
// query-16), swapped-operand QK^T, P-in-registers PV, XOR-swizzled K/V^T
// (gll16 linear dest + pre-swizzled src + swizzled read), T13
// defer-rescale, setprio on MFMA, LDS end-merge.

#define HD 128
#define BR 64
#define BC 128

typedef __attribute__((ext_vector_type(8))) short short8;
typedef __attribute__((ext_vector_type(4))) float floatx4;

__device__ inline unsigned packbf2(float lo, float hi) {
    __hip_bfloat162 h2 = __float22bfloat162_rn(make_float2(lo, hi));
    return *reinterpret_cast<unsigned*>(&h2);   // low16 = lo, high16 = hi
}
__device__ inline short bfs(float f) {
    __hip_bfloat16 b = __float2bfloat16(f);
    return *reinterpret_cast<short*>(&b);
}
__device__ inline float fexp2(float x) { return __builtin_amdgcn_exp2f(x); }

__device__ inline void gll16(const void* g, void* l) {
    __builtin_amdgcn_global_load_lds(
        (const __attribute__((address_space(1))) unsigned int*)g,
        (__attribute__((address_space(3))) unsigned int*)l, 16, 0, 0);
}

// ------- prepack: fp32 -> bf16, swizzled, XCD-LOCAL (writer bid&7==h) -----
__global__ __launch_bounds__(256) void prepack(
    const float* __restrict__ K, const float* __restrict__ V,
    unsigned short* __restrict__ wsK, unsigned short* __restrict__ wsVT,
    int S)
{
    const int tid = threadIdx.x;
    const int nVblk = 8 * (S >> 6);
    const int bid = blockIdx.x;
    if (bid < nVblk) {
        // V^T via LDS: block = (h = bid&7, t = bid>>3)  [XCD-local]
        __shared__ __align__(8) unsigned short sV[HD * 68];  // [d][r], stride 68 bf16
        const int ntile = S >> 6;
        const int h = bid & 7;
        const int t = bid >> 3;
        const float* vb = V + ((size_t)h * S + t * 64) * HD;
        {
            const int rp = tid >> 3;
            const int dc = tid & 7;
            const int r0 = rp * 2;
            const int d0 = dc * 16;
            const float* p0 = vb + (size_t)r0 * HD + d0;
            const float* p1 = p0 + HD;
            float4 a0 = *(const float4*)(p0 + 0),  a1 = *(const float4*)(p0 + 4);
            float4 a2 = *(const float4*)(p0 + 8),  a3 = *(const float4*)(p0 + 12);
            float4 b0 = *(const float4*)(p1 + 0),  b1 = *(const float4*)(p1 + 4);
            float4 b2 = *(const float4*)(p1 + 8),  b3 = *(const float4*)(p1 + 12);
            float av[16] = {a0.x,a0.y,a0.z,a0.w, a1.x,a1.y,a1.z,a1.w,
                            a2.x,a2.y,a2.z,a2.w, a3.x,a3.y,a3.z,a3.w};
            float bv[16] = {b0.x,b0.y,b0.z,b0.w, b1.x,b1.y,b1.z,b1.w,
                            b2.x,b2.y,b2.z,b2.w, b3.x,b3.y,b3.z,b3.w};
            #pragma unroll
            for (int i = 0; i < 16; ++i) {
                unsigned pr = packbf2(av[i], bv[i]);   // keys r0 (lo), r0+1 (hi)
                *(unsigned*)((char*)sV + ((size_t)(d0 + i) * 68 + r0) * 2) = pr;
            }
        }
        __syncthreads();
        const int d  = tid >> 1;
        const int jj = tid & 1;
        char* dstrow = (char*)wsVT + (((size_t)(h * ntile + t) * HD + d) * 128);
        const int dx = (d & 7) << 4;
        const unsigned short* srow = sV + (size_t)d * 68;
        #pragma unroll
        for (int u = 0; u < 4; ++u) {
            const int j  = jj * 4 + u;
            const int k0 = (j >> 2) * 32 + (j & 3) * 4;
            uint2 lo = *(const uint2*)(srow + k0);        // keys k0..k0+3
            uint2 hi = *(const uint2*)(srow + k0 + 16);   // keys k0+16..k0+19
            uint4 w = make_uint4(lo.x, lo.y, hi.x, hi.y);
            *(uint4*)(dstrow + ((j * 16) ^ dx)) = w;
        }
    } else {
        // K: block = (h = b2&7, idx = b2>>3)  [XCD-local]
        const int b2  = bid - nVblk;
        const int h   = b2 & 7;
        const int idx = b2 >> 3;                // 0..(S*16/256)-1
        const int cid = idx * 256 + tid;        // chunk id within head
        const int rowh = cid >> 4;
        const int c    = cid & 15;
        const size_t row = (size_t)h * S + rowh;
        const float* src = K + row * HD + c * 8;
        float4 f0 = *(const float4*)src;
        float4 f1 = *(const float4*)(src + 4);
        union { uint4 q; unsigned u[4]; } w;
        w.u[0] = packbf2(f0.x, f0.y); w.u[1] = packbf2(f0.z, f0.w);
        w.u[2] = packbf2(f1.x, f1.y); w.u[3] = packbf2(f1.z, f1.w);
        *(uint4*)((char*)wsK + row * 256 + ((c * 16) ^ ((rowh & 7) << 4))) = w.q;
    }
}

// ---------------- main attention kernel (R19 structure) ----------------
__global__ __launch_bounds__(512, 1) void fa_fwd(
    const float* __restrict__ Q,
    const unsigned short* __restrict__ wsK,
    const unsigned short* __restrict__ wsVT,
    const int* __restrict__ cu_seqlens, int n_cu,
    float* __restrict__ O,
    int S)
{
    __shared__ alignas(16) __hip_bfloat16 sK2[2][BC * HD];      // 2 x 32KB
    __shared__ alignas(16) unsigned int   sVT2[2][2 * HD * 32]; // 2 x 32KB

    const int tid  = threadIdx.x;
    const int wave = tid >> 6;
    const int gp   = wave >> 2;             // key-half group 0/1 (64 keys each)
    const int wsub = wave & 3;              // query sub-block 0..3
    const int lane = tid & 63;
    const int quad = lane >> 4;
    const int l16  = lane & 15;
    const int kx   = (l16 & 7) << 4;        // read-side XOR (matches prepack)

    const int nqb = S / BR;
    const int h   = blockIdx.x & 7;         // head -> XCD (matches prepack)
    const int g   = (int)(blockIdx.x >> 3);
    int qb;
    if (nqb == 64) qb = (g & 3) * 16 + (15 - (g >> 2));   // LPT: nt desc
    else           qb = nqb - 1 - g;
    const int q0    = qb * BR;
    const int qw    = q0 + wsub * 16;
    const int qlane = qw + l16;

    int blk_ds = 0;
    for (int i = 0; i < n_cu; ++i) {
        int c = cu_seqlens[i];
        if (c <= q0) blk_ds = c;
    }
    const int k_begin = blk_ds & ~(BC - 1);
    const int ntiles  = (q0 + BR - 1 - k_begin) / BC + 1;

    const char* gkb = (const char*)wsK + (size_t)h * S * 256;
    const char* gvb = (const char*)wsVT + (size_t)h * (S >> 6) * 16384;
    const int wofs = (wave & 3) * 8192;
    const int lo = wofs + lane * 16;
    auto stage = [&](int kt, int buf) {
        if (gp == 0) {
            const char* gk = gkb + (size_t)kt * 256 + lo;
            char* lk = (char*)&sK2[buf][0] + wofs;
            #pragma unroll
            for (int c = 0; c < 8; ++c) gll16(gk + c * 1024, lk + c * 1024);
        } else {
            const char* gv = gvb + (size_t)(kt >> 6) * 16384 + lo;
            char* lv = (char*)&sVT2[buf][0] + wofs;
            #pragma unroll
            for (int c = 0; c < 8; ++c) gll16(gv + c * 1024, lv + c * 1024);
        }
    };

    const size_t hoff = (size_t)h * S * HD;
    const float* Qh = Q + hoff;
    float*       Oh = O + hoff;

    // ---- Q fragments, with sl*log2e FOLDED IN (scores born pre-scaled) ----
    const float sl = 0.08838834764831845f * 1.4426950408889634f;
    short8 aq[4];
    {
        const float* qp = Qh + (size_t)qlane * HD + quad * 8;
        #pragma unroll
        for (int ks = 0; ks < 4; ++ks) {
            float4 a0 = *(const float4*)(qp + ks * 32);
            float4 a1 = *(const float4*)(qp + ks * 32 + 4);
            short8 a;
            a[0] = bfs(a0.x * sl); a[1] = bfs(a0.y * sl);
            a[2] = bfs(a0.z * sl); a[3] = bfs(a0.w * sl);
            a[4] = bfs(a1.x * sl); a[5] = bfs(a1.y * sl);
            a[6] = bfs(a1.z * sl); a[7] = bfs(a1.w * sl);
            aq[ks] = a;
        }
    }

    int ds_lane = 0;
    for (int i = 0; i < n_cu; ++i) {
        int c = cu_seqlens[i];
        if (c <= qlane) ds_lane = c;
    }

    stage(k_begin, 0);

    floatx4 oacc[8];
    #pragma unroll
    for (int dt = 0; dt < 8; ++dt) oacc[dt] = (floatx4){0.f, 0.f, 0.f, 0.f};
    float m_r = -1e30f, l_r = 0.f;

    for (int it = 0; it < ntiles; ++it) {
        const int kt  = k_begin + it * BC;
        const int buf = it & 1;

        // stage(it) was issued a full step earlier: vmcnt(0) ~free drain.
        asm volatile("s_waitcnt vmcnt(0)\n\ts_barrier" ::: "memory");
        if (it + 1 < ntiles) stage(kt + BC, buf ^ 1);

        if (kt + gp * 64 <= qw + 15) {
            const char* kbase = (const char*)&sK2[buf][0];
            const char* vbase = (const char*)&sVT2[buf][0] + gp * 16384;

            // ---- S^T = K Q^T over this wave's 64 keys (4 ct blocks) ----
            floatx4 sc[4];
            __builtin_amdgcn_s_setprio(1);
            #pragma unroll
            for (int ctl = 0; ctl < 4; ++ctl) {
                if (kt + gp * 64 + ctl * 16 <= qw + 15) {
                    floatx4 c = (floatx4){0.f, 0.f, 0.f, 0.f};
                    #pragma unroll
                    for (int ks = 0; ks < 4; ++ks) {
                        short8 a = *(const short8*)(kbase
                            + (gp * 64 + ctl * 16 + l16) * 256
                            + (((ks * 4 + quad) << 4) ^ kx));
                        c = __builtin_amdgcn_mfma_f32_16x16x32_bf16(a, aq[ks], c, 0, 0, 0);
                    }
                    sc[ctl] = c;
                } else {
                    sc[ctl] = (floatx4){-1e30f, -1e30f, -1e30f, -1e30f};
                }
            }
            __builtin_amdgcn_s_setprio(0);

            // ---- mask ONLY partial blocks (wave-uniform full test) ----
            #pragma unroll
            for (int ctl = 0; ctl < 4; ++ctl) {
                const int kc = kt + gp * 64 + ctl * 16;
                if (kc <= qw + 15 && !(kc + 15 <= qw && kc >= blk_ds)) {
                    #pragma unroll
                    for (int r = 0; r < 4; ++r) {
                        const int key = kc + quad * 4 + r;
                        const bool valid = (key <= qlane) && (key >= ds_lane);
                        sc[ctl][r] = valid ? sc[ctl][r] : -1e30f;
                    }
                }
            }

            // ---- online softmax over 16 values + 2 shfl ----
            float mx01 = fmaxf(fmaxf(fmaxf(sc[0][0], sc[0][1]), fmaxf(sc[0][2], sc[0][3])),
                               fmaxf(fmaxf(sc[1][0], sc[1][1]), fmaxf(sc[1][2], sc[1][3])));
            float mx23 = fmaxf(fmaxf(fmaxf(sc[2][0], sc[2][1]), fmaxf(sc[2][2], sc[2][3])),
                               fmaxf(fmaxf(sc[3][0], sc[3][1]), fmaxf(sc[3][2], sc[3][3])));
            float mx = fmaxf(mx01, mx23);
            mx = fmaxf(mx, __shfl_xor(mx, 16, 64));
            mx = fmaxf(mx, __shfl_xor(mx, 32, 64));

            // T13 defer-rescale
            if (__any(mx > m_r + 8.f)) {
                const float mnew = fmaxf(m_r, mx);
                const float al   = fexp2(m_r - mnew);
                m_r = mnew;
                l_r *= al;
                #pragma unroll
                for (int dt = 0; dt < 8; ++dt) {
                    #pragma unroll
                    for (int r = 0; r < 4; ++r)
                        oacc[dt][r] *= al;
                }
            }
            const float live = (m_r > -1e29f) ? 1.f : 0.f;

            float ssum = 0.f;
            #pragma unroll
            for (int ctl = 0; ctl < 4; ++ctl) {
                #pragma unroll
                for (int r = 0; r < 4; ++r) {
                    float p = fexp2(sc[ctl][r] - m_r) * live;
                    sc[ctl][r] = p;
                    ssum += p;
                }
            }
            l_r += ssum;

            // ---- O^T += V^T P^T over this wave's 64-key V tile ----
            __builtin_amdgcn_s_setprio(1);
            #pragma unroll
            for (int ks = 0; ks < 2; ++ks) {
                if (kt + gp * 64 + ks * 32 <= qw + 15) {
                    union { unsigned u[4]; short8 s; } pu;
                    pu.u[0] = packbf2(sc[2*ks][0],   sc[2*ks][1]);
                    pu.u[1] = packbf2(sc[2*ks][2],   sc[2*ks][3]);
                    pu.u[2] = packbf2(sc[2*ks+1][0], sc[2*ks+1][1]);
                    pu.u[3] = packbf2(sc[2*ks+1][2], sc[2*ks+1][3]);
                    #pragma unroll
                    for (int dt = 0; dt < 8; ++dt) {
                        union { uint4 q; short8 s; } cv;
                        cv.q = *(const uint4*)(vbase + (dt * 16 + l16) * 128
                                               + (((ks * 4 + quad) << 4) ^ kx));
                        oacc[dt] = __builtin_amdgcn_mfma_f32_16x16x32_bf16(cv.s, pu.s, oacc[dt], 0, 0, 0);
                    }
                }
            }
            __builtin_amdgcn_s_setprio(0);
        }
    }

    l_r += __shfl_xor(l_r, 16, 64);
    l_r += __shfl_xor(l_r, 32, 64);

    __syncthreads();

    float* obuf = (float*)&sK2[0][0];
    float* lbuf = (float*)&sVT2[0][0];
    if (gp == 1) {
        float* ob = obuf + wsub * 2048;
        #pragma unroll
        for (int dt = 0; dt < 8; ++dt) {
            const int sw = (dt ^ (lane & 7)) << 2;
            float4 st;
            st.x = oacc[dt][0]; st.y = oacc[dt][1];
            st.z = oacc[dt][2]; st.w = oacc[dt][3];
            *(float4*)(ob + lane * 32 + sw) = st;
        }
        if (quad == 0) {
            lbuf[wsub * 128 + l16]      = m_r;
            lbuf[wsub * 128 + 64 + l16] = l_r;
        }
    }
    __syncthreads();
    if (gp == 0) {
        const float m2 = lbuf[wsub * 128 + l16];
        const float l2 = lbuf[wsub * 128 + 64 + l16];
        const float M  = fmaxf(m_r, m2);
        const float w1 = fexp2(m_r - M);
        const float w2 = fexp2(m2 - M);
        const float inv = 1.0f / (w1 * l_r + w2 * l2);
        const float* ob = obuf + wsub * 2048;
        float* op = Oh + (size_t)qlane * HD + quad * 4;
        #pragma unroll
        for (int dt = 0; dt < 8; ++dt) {
            const int sw = (dt ^ (lane & 7)) << 2;
            float4 o2 = *(const float4*)(ob + lane * 32 + sw);
            float4 st;
            st.x = (w1 * oacc[dt][0] + w2 * o2.x) * inv;
            st.y = (w1 * oacc[dt][1] + w2 * o2.y) * inv;
            st.z = (w1 * oacc[dt][2] + w2 * o2.z) * inv;
            st.w = (w1 * oacc[dt][3] + w2 * o2.w) * inv;
            *(float4*)(op + dt * 16) = st;
        }
    }
}

extern "C" void kernel_launch(void* const* d_in, const int* in_sizes, int n_in,
                              void* d_out, int out_size, void* d_ws, size_t ws_size,
                              hipStream_t stream) {
    const float* q = (const float*)d_in[0];
    const float* k = (const float*)d_in[1];
    const float* v = (const float*)d_in[2];
    const int* cu = (const int*)d_in[3];
    const int n_cu = in_sizes[3];
    const int H = 8;
    const int S = in_sizes[0] / (H * HD);   // B=1
    float* out = (float*)d_out;

    const int nqb = S / BR;
    unsigned short* wsK  = (unsigned short*)d_ws;                 // H*S*256 B
    unsigned short* wsVT = wsK + (size_t)H * S * HD;              // H*S*256 B

    const int nVblk = H * (S >> 6);          // 512 (V blocks first)
    const int nKblk = (H * S) / 16;          // 2048
    prepack<<<dim3(nVblk + nKblk), dim3(256), 0, stream>>>(k, v, wsK, wsVT, S);

    dim3 grid(H * nqb);        // 512 blocks, 1 per CU resident (128KB LDS)
    dim3 block(512);           // 8 waves
    fa_fwd<<<grid, block, 0, stream>>>(q, wsK, wsVT, cu, n_cu, out, S);
}